// Round 1
// baseline (6522.399 us; speedup 1.0000x reference)
//
#include <hip/hip_runtime.h>

typedef float vf4 __attribute__((ext_vector_type(4)));

#define BB   16    // batch rows per block
#define NT   256   // threads per block
#define TT   128   // timesteps
#define II   28    // input features
#define HH   200   // hidden
#define JP   208   // padded hidden (13*16)
#define KP   208   // padded K for recurrent part
#define KT   52    // k-tile (208 = 4*52, multiple of 4)
#define SA   244   // A stride in words: cols 0..207 = h, 208..235 = x_t
#define SW   52    // Wt stride in words

// LDS: A 16*244*4 = 15616 B, Wt 208*52*4 = 43264 B, bsum 208*4 = 832 B
// total 59712 B < 64 KB  -> 2 blocks/CU (119424 < 163840), 8 waves/CU balanced 2/SIMD.

__global__ __launch_bounds__(NT, 2)
void rnn_fused(const float* __restrict__ x,
               const float* __restrict__ W_ih,
               const float* __restrict__ W_hh,
               const float* __restrict__ b_ih,
               const float* __restrict__ b_hh,
               const float* __restrict__ W_fc,
               const float* __restrict__ b_fc,
               float* __restrict__ out)
{
    __shared__ float A[BB * SA];
    __shared__ float Wt[JP * SW];
    __shared__ float bsum[JP];

    const int tid = threadIdx.x;
    const int r   = tid & 15;        // batch row within block
    const int jg  = tid >> 4;        // 0..15, output j = jg + 16*jj, jj<13
    const long b0 = (long)blockIdx.x * BB;

    // init h (and pad cols) to zero; stage combined bias
    for (int v = tid; v < BB * SA; v += NT) A[v] = 0.0f;
    for (int v = tid; v < JP; v += NT)
        bsum[v] = (v < HH) ? (b_ih[v] + b_hh[v]) : 0.0f;
    __syncthreads();

    float acc[13];

    for (int t = 0; t < TT; ++t) {
        // ---- stage x_t into A[., 208..235] (streamed once -> nontemporal) ----
        for (int f = tid; f < BB * II; f += NT) {
            int rr = f / II, c = f - rr * II;
            A[rr * SA + KP + c] =
                __builtin_nontemporal_load(&x[((b0 + rr) * TT + t) * II + c]);
        }
        __syncthreads();   // A: x_t visible; prev-step h writes visible; prev Wt reads done

        #pragma unroll
        for (int jj = 0; jj < 13; ++jj) acc[jj] = bsum[jg + 16 * jj];

        // ---- input projection: k over 28, W_ih from global (L1-hot, 22.4 KB) ----
        #pragma unroll
        for (int kk = 0; kk < II; kk += 4) {
            const vf4 av = *(const vf4*)&A[r * SA + KP + kk];
            #pragma unroll
            for (int jj = 0; jj < 13; ++jj) {
                const int j = jg + 16 * jj;
                vf4 wv = {0.f, 0.f, 0.f, 0.f};
                if (j < HH) wv = *(const vf4*)&W_ih[j * II + kk];
                acc[jj] = fmaf(av.x, wv.x, acc[jj]);
                acc[jj] = fmaf(av.y, wv.y, acc[jj]);
                acc[jj] = fmaf(av.z, wv.z, acc[jj]);
                acc[jj] = fmaf(av.w, wv.w, acc[jj]);
            }
        }

        // ---- recurrent: 4 k-tiles of 52 over padded K=208 ----
        for (int kt = 0; kt < 4; ++kt) {
            if (kt > 0) __syncthreads();      // WAR: prior tile's readers done before restage
            const int k0 = kt * KT;
            // stage Wt, permuted rows: storage s holds global row j=(s%13)*16 + s/13
            for (int v = tid; v < JP * (KT / 4); v += NT) {   // 2704 float4s
                int s   = v / 13;
                int c4  = v - s * 13;
                int jsrc = (s % 13) * 16 + (s / 13);
                int kc  = k0 + c4 * 4;
                vf4 w = {0.f, 0.f, 0.f, 0.f};
                if (jsrc < HH && kc < HH)      // kc%4==0 and 200%4==0 -> full vec in-bounds
                    w = *(const vf4*)&W_hh[jsrc * HH + kc];
                *(vf4*)&Wt[s * SW + c4 * 4] = w;
            }
            __syncthreads();  // B: tile visible

            const int wbase = jg * 13 * SW;
            for (int kb = 0; kb < KT; kb += 4) {
                const vf4 av = *(const vf4*)&A[r * SA + k0 + kb];
                #pragma unroll
                for (int jj = 0; jj < 13; ++jj) {
                    const vf4 wv = *(const vf4*)&Wt[wbase + jj * SW + kb];
                    acc[jj] = fmaf(av.x, wv.x, acc[jj]);
                    acc[jj] = fmaf(av.y, wv.y, acc[jj]);
                    acc[jj] = fmaf(av.z, wv.z, acc[jj]);
                    acc[jj] = fmaf(av.w, wv.w, acc[jj]);
                }
            }
        }
        __syncthreads();  // E: all h reads done -> safe to overwrite h

        #pragma unroll
        for (int jj = 0; jj < 13; ++jj) {
            float v = acc[jj];
            A[r * SA + jg + 16 * jj] = v > 0.0f ? v : 0.0f;   // relu; pad cols get 0
        }
    }
    __syncthreads();

    // ---- final FC: out[b][o] = h @ W_fc[o] + b_fc[o] ----
    if (tid < BB * 10) {
        int rr = tid & 15;
        int o  = tid >> 4;
        float s = b_fc[o];
        for (int k = 0; k < HH; ++k)
            s = fmaf(A[rr * SA + k], W_fc[o * HH + k], s);
        __builtin_nontemporal_store(s, &out[(b0 + rr) * 10 + o]);
    }
}

extern "C" void kernel_launch(void* const* d_in, const int* in_sizes, int n_in,
                              void* d_out, int out_size, void* d_ws, size_t ws_size,
                              hipStream_t stream) {
    const float* x    = (const float*)d_in[0];
    const float* W_ih = (const float*)d_in[1];
    const float* W_hh = (const float*)d_in[2];
    const float* b_ih = (const float*)d_in[3];
    const float* b_hh = (const float*)d_in[4];
    const float* W_fc = (const float*)d_in[5];
    const float* b_fc = (const float*)d_in[6];
    float* out = (float*)d_out;

    rnn_fused<<<dim3(8192 / BB), dim3(NT), 0, stream>>>(
        x, W_ih, W_hh, b_ih, b_hh, W_fc, b_fc, out);
}

// Round 2
// 322.623 us; speedup vs baseline: 20.2168x; 20.2168x over previous
//
#include <hip/hip_runtime.h>

typedef float  f4v __attribute__((ext_vector_type(4)));
typedef float  f2v __attribute__((ext_vector_type(2)));
typedef short  s8v __attribute__((ext_vector_type(8)));

#define TT  128
#define II  28
#define HH  200
#define BB  16          // batch rows per block
#define NT  256         // 4 waves
#define SH  264         // Hs stride in bf16 elems: 256 cols + 8 pad (bank-friendly: 132 words, 132%32=4)
#define KHX 208         // combined-K offset where x-part starts
#define SF  212         // Hf stride in floats (212%32=20 -> 2-way on r,r+8: free)

// f32 -> bf16 bits, round-to-nearest-even (no NaN handling needed here)
__device__ __forceinline__ short f2bf(float f) {
    union { float f; unsigned u; } a; a.f = f;
    unsigned r = a.u + 0x7FFFu + ((a.u >> 16) & 1u);
    return (short)(r >> 16);
}

__global__ __launch_bounds__(NT, 2)
void rnn_mfma(const float* __restrict__ x,
              const float* __restrict__ W_ih,
              const float* __restrict__ W_hh,
              const float* __restrict__ b_ih,
              const float* __restrict__ b_hh,
              const float* __restrict__ W_fc,
              const float* __restrict__ b_fc,
              float* __restrict__ out)
{
    // LDS: Hs 16*264*2=8448 B, Hf 16*212*4=13568 B, bsum 832 B  => ~22.9 KB
    __shared__ short Hs[BB][SH];   // bf16 bits: cols 0..207 = h (200..207 pad=0), 208..235 = x_t, 236..255 = 0
    __shared__ float Hf[BB][SF];   // final h in fp32 for the FC epilogue
    __shared__ float bsum[208];

    const int tid  = threadIdx.x;
    const int lane = tid & 63;
    const int q    = lane >> 4;    // quad-group 0..3
    const int lr   = lane & 15;    // A: j within tile; B: batch row; C: col = batch row
    const int wave = tid >> 6;
    const int b0   = blockIdx.x * BB;

    // j-tile split over 4 waves: {4,3,3,3} of 13 tiles (JP=208)
    const int first = (wave == 0) ? 0 : 1 + 3 * wave;
    const int cnt   = (wave == 0) ? 4 : 3;

    // ---- prologue: zero Hs, build bsum ----
    for (int i = tid; i < BB * SH / 2; i += NT) ((int*)Hs)[i] = 0;
    for (int j = tid; j < 208; j += NT) bsum[j] = (j < HH) ? b_ih[j] + b_hh[j] : 0.0f;

    // ---- load W~ fragments into registers (resident whole kernel) ----
    // A-frag(jt,kc): lane holds W~[j = 16*jt + lr][k = 32*kc + 8*q + i], i=0..7
    // W~[j][k] = W_hh[j][k] (k<200), W_ih[j][k-208] (208<=k<236), else 0
    s8v Af[4][8];
    #pragma unroll
    for (int u = 0; u < 4; ++u) {
        const int j = 16 * (first + u) + lr;
        #pragma unroll
        for (int kc = 0; kc < 8; ++kc) {
            const int k0 = 32 * kc + 8 * q;
            union { short s[8]; s8v v; } tv;
            #pragma unroll
            for (int i = 0; i < 8; ++i) {
                const int k = k0 + i;
                float w = 0.0f;
                if (u < cnt && j < HH) {
                    if (k < HH)                      w = W_hh[j * HH + k];
                    else if (k >= KHX && k < KHX+II) w = W_ih[j * II + (k - KHX)];
                }
                tv.s[i] = f2bf(w);
            }
            Af[u][kc] = tv.v;
        }
    }
    __syncthreads();   // zeroed Hs + bsum visible

    // ---- per-lane bias vectors (C rows = j = 16*jt + 4*q + i) ----
    f4v biasv[4];
    #pragma unroll
    for (int u = 0; u < 4; ++u) {
        const int jt = first + ((u < cnt) ? u : 0);
        biasv[u] = *(const f4v*)&bsum[16 * jt + 4 * q];
    }

    // ---- stage x_0; prefetch x_1 (distance-2 pipeline) ----
    const int xr = tid / 14, xc = 2 * (tid % 14);   // threads 0..223 own one float2 of x_t
    f2v xcur = {0.f, 0.f}, xnxt = {0.f, 0.f};
    if (tid < 224) {
        f2v v0 = __builtin_nontemporal_load((const f2v*)&x[((b0 + xr) * TT + 0) * II + xc]);
        *(int*)&Hs[xr][KHX + xc] = (f2bf(v0.x) & 0xffff) | (f2bf(v0.y) << 16);
        xcur = __builtin_nontemporal_load((const f2v*)&x[((b0 + xr) * TT + 1) * II + xc]);
    }
    __syncthreads();   // x_0 staged (after zeroing barrier above -> no race)

    // ---- recurrence ----
    for (int t = 0; t < TT; ++t) {
        // prefetch x_{t+2} (consumed at iter t+1's write phase)
        if (tid < 224) {
            const int tn = (t + 2 < TT) ? t + 2 : TT - 1;
            xnxt = __builtin_nontemporal_load((const f2v*)&x[((b0 + xr) * TT + tn) * II + xc]);
        }

        f4v acc[4];
        #pragma unroll
        for (int u = 0; u < 4; ++u) acc[u] = biasv[u];

        // D[j][r] += sum_k W~[j][k] * h|x[r][k],  K = 256 in 8 chunks
        #pragma unroll
        for (int kc = 0; kc < 8; ++kc) {
            const s8v bf = *(const s8v*)&Hs[lr][32 * kc + 8 * q];
            #pragma unroll
            for (int u = 0; u < 4; ++u)
                if (u < cnt)
                    acc[u] = __builtin_amdgcn_mfma_f32_16x16x32_bf16(Af[u][kc], bf, acc[u], 0, 0, 0);
        }
        __syncthreads();   // all lanes done reading Hs for step t

        // write h_{t+1} = relu(acc): lane holds j = 16*jt + 4*q + {0..3}, r = lr -> packed b64
        #pragma unroll
        for (int u = 0; u < 4; ++u) {
            if (u < cnt) {
                const int jt = first + u;
                const f4v a = acc[u];
                const float r0 = fmaxf(a.x, 0.f), r1 = fmaxf(a.y, 0.f);
                const float r2 = fmaxf(a.z, 0.f), r3 = fmaxf(a.w, 0.f);
                short4 hv;
                hv.x = f2bf(r0); hv.y = f2bf(r1); hv.z = f2bf(r2); hv.w = f2bf(r3);
                *(short4*)&Hs[lr][16 * jt + 4 * q] = hv;
                if (t == TT - 1) {
                    f4v rf = {r0, r1, r2, r3};
                    *(f4v*)&Hf[lr][16 * jt + 4 * q] = rf;
                }
            }
        }
        // write x_{t+1}
        if (t < TT - 1 && tid < 224)
            *(int*)&Hs[xr][KHX + xc] = (f2bf(xcur.x) & 0xffff) | (f2bf(xcur.y) << 16);
        xcur = xnxt;
        __syncthreads();   // h_{t+1}, x_{t+1} visible
    }

    // ---- FC epilogue in fp32: out[b][o] = h_T @ W_fc[o] + b_fc[o] ----
    if (tid < BB * 10) {
        const int o = tid >> 4, r = tid & 15;
        float s = b_fc[o];
        for (int k = 0; k < HH; ++k)
            s = fmaf(Hf[r][k], W_fc[o * HH + k], s);
        __builtin_nontemporal_store(s, &out[(b0 + r) * 10 + o]);
    }
}

extern "C" void kernel_launch(void* const* d_in, const int* in_sizes, int n_in,
                              void* d_out, int out_size, void* d_ws, size_t ws_size,
                              hipStream_t stream) {
    const float* x    = (const float*)d_in[0];
    const float* W_ih = (const float*)d_in[1];
    const float* W_hh = (const float*)d_in[2];
    const float* b_ih = (const float*)d_in[3];
    const float* b_hh = (const float*)d_in[4];
    const float* W_fc = (const float*)d_in[5];
    const float* b_fc = (const float*)d_in[6];
    float* out = (float*)d_out;

    rnn_mfma<<<dim3(8192 / BB), dim3(NT), 0, stream>>>(
        x, W_ih, W_hh, b_ih, b_hh, W_fc, b_fc, out);
}

// Round 3
// 318.454 us; speedup vs baseline: 20.4814x; 1.0131x over previous
//
#include <hip/hip_runtime.h>

typedef float f4v __attribute__((ext_vector_type(4)));
typedef short s8v __attribute__((ext_vector_type(8)));

#define TT 128
#define II 28
#define HH 200
#define BB 16     // batch rows per block
#define NT 256    // 4 waves
#define SH 232    // Hs row stride in bf16 elems: 464 B (16B-aligned rows); 116 words %32=20 -> h-writes 2-way (free)
#define KX 224    // K offset where x block starts (kc7 = K 224..255)
#define SF 212    // Hf stride in floats

// f32 -> bf16 bits, round-to-nearest-even
__device__ __forceinline__ short f2bf(float f) {
    union { float f; unsigned u; } a; a.f = f;
    unsigned r = a.u + 0x7FFFu + ((a.u >> 16) & 1u);
    return (short)(r >> 16);
}

__global__ __launch_bounds__(NT, 2)
void rnn_mfma2(const float* __restrict__ x,
               const float* __restrict__ W_ih,
               const float* __restrict__ W_hh,
               const float* __restrict__ b_ih,
               const float* __restrict__ b_hh,
               const float* __restrict__ W_fc,
               const float* __restrict__ b_fc,
               float* __restrict__ out)
{
    // LDS: Hs 2*16*232*2 = 14848 B, Hf 16*212*4 = 13568 B  => ~27.8 KB
    __shared__ __align__(16) short Hs[2][BB][SH]; // bf16 h: cols 0..199, pad 200..231 = 0
    __shared__ __align__(16) float Hf[BB][SF];    // final h fp32 for FC

    const int tid  = threadIdx.x;
    const int lane = tid & 63;
    const int q    = lane >> 4;     // quad 0..3
    const int lr   = lane & 15;     // A: j-within-tile ; B: batch row ; C: col = batch row
    const int wave = tid >> 6;
    const int b0   = blockIdx.x * BB;

    // j-tile split over 4 waves: {4,3,3,3} of 13 tiles (J padded to 208)
    const int first = (wave == 0) ? 0 : 1 + 3 * wave;
    const int cnt   = (wave == 0) ? 4 : 3;

    // ---- zero both Hs buffers (h0 = 0, pads = 0) ----
    for (int i = tid; i < 2 * BB * SH / 2; i += NT) ((int*)Hs)[i] = 0;

    // ---- W~ fragments resident in registers ----
    // A-frag(jt,kc): lane holds W~[j=16*jt+lr][k=32*kc+8*q+i], i=0..7
    // W~[j][k] = W_hh[j][k] (k<200) | W_ih[j][k-224] (224<=k<252) | 0
    s8v Af[4][8];
    #pragma unroll
    for (int u = 0; u < 4; ++u) {
        const int j = 16 * (first + u) + lr;
        #pragma unroll
        for (int kc = 0; kc < 8; ++kc) {
            const int k0 = 32 * kc + 8 * q;
            union { short s[8]; s8v v; } tv;
            #pragma unroll
            for (int i = 0; i < 8; ++i) {
                const int k = k0 + i;
                float w = 0.0f;
                if (u < cnt && j < HH) {
                    if (k < HH)                     w = W_hh[j * HH + k];
                    else if (k >= KX && k < KX+II)  w = W_ih[j * II + (k - KX)];
                }
                tv.s[i] = f2bf(w);
            }
            Af[u][kc] = tv.v;
        }
    }

    // ---- per-lane bias (C rows j = 16*jt + 4*q + i) ----
    f4v biasv[4];
    #pragma unroll
    for (int u = 0; u < 4; ++u) {
        const int jt = first + u;
        f4v bv = {0.f, 0.f, 0.f, 0.f};
        #pragma unroll
        for (int i = 0; i < 4; ++i) {
            const int j = 16 * jt + 4 * q + i;
            if (u < cnt && j < HH) bv[i] = b_ih[j] + b_hh[j];
        }
        biasv[u] = bv;
    }

    // ---- x pipeline: lane (lr,q) holds x[b0+lr][t][8q..8q+7] (cols>=28 -> 0) ----
    const float* xp = x + (long)(b0 + lr) * TT * II + 8 * q;
    f4v xa0 = {0,0,0,0}, xb0 = {0,0,0,0}, xa1 = {0,0,0,0}, xb1 = {0,0,0,0};
    xa0 = *(const f4v*)(xp);
    if (q != 3) xb0 = *(const f4v*)(xp + 4);
    xa1 = *(const f4v*)(xp + II);
    if (q != 3) xb1 = *(const f4v*)(xp + II + 4);

    __syncthreads();   // zeroed Hs visible

    // ---- one timestep: read Hs[pb], write Hs[pb^1]; ONE barrier ----
    auto step = [&](int t, int pb, f4v& xa, f4v& xb) {
        // build x B-frag early, then immediately reissue the slot's load for t+2
        union { short s[8]; s8v v; } xf;
        #pragma unroll
        for (int i = 0; i < 4; ++i) { xf.s[i] = f2bf(xa[i]); xf.s[4+i] = f2bf(xb[i]); }
        {
            const int tn = (t + 2 < TT) ? t + 2 : TT - 1;
            xa = *(const f4v*)(xp + tn * II);
            if (q != 3) xb = *(const f4v*)(xp + tn * II + 4);
        }

        f4v acc[4];
        #pragma unroll
        for (int u = 0; u < 4; ++u) acc[u] = biasv[u];

        #pragma unroll
        for (int kc = 0; kc < 7; ++kc) {
            const s8v bf = *(const s8v*)&Hs[pb][lr][32 * kc + 8 * q];
            #pragma unroll
            for (int u = 0; u < 4; ++u)
                if (u < cnt)
                    acc[u] = __builtin_amdgcn_mfma_f32_16x16x32_bf16(Af[u][kc], bf, acc[u], 0, 0, 0);
        }
        #pragma unroll
        for (int u = 0; u < 4; ++u)
            if (u < cnt)
                acc[u] = __builtin_amdgcn_mfma_f32_16x16x32_bf16(Af[u][7], xf.v, acc[u], 0, 0, 0);

        // relu -> bf16 -> Hs[pb^1]; lane holds j = 16*jt+4q+{0..3}, r = lr (packed b64)
        #pragma unroll
        for (int u = 0; u < 4; ++u) {
            if (u < cnt) {
                const int jt = first + u;
                const f4v a = acc[u];
                const float r0 = fmaxf(a.x, 0.f), r1 = fmaxf(a.y, 0.f);
                const float r2 = fmaxf(a.z, 0.f), r3 = fmaxf(a.w, 0.f);
                short4 hv;
                hv.x = f2bf(r0); hv.y = f2bf(r1); hv.z = f2bf(r2); hv.w = f2bf(r3);
                *(short4*)&Hs[pb ^ 1][lr][16 * jt + 4 * q] = hv;
                if (t == TT - 1) {
                    f4v rf = {r0, r1, r2, r3};
                    *(f4v*)&Hf[lr][16 * jt + 4 * q] = rf;
                }
            }
        }
        __syncthreads();   // writes (and this step's reads) complete
    };

    for (int tb = 0; tb < TT; tb += 2) {
        step(tb,     0, xa0, xb0);
        step(tb + 1, 1, xa1, xb1);
    }

    // ---- FC epilogue (fp32): out[b][o] = h_T . W_fc[o] + b_fc[o] ----
    if (tid < BB * 10) {
        const int o = tid >> 4, r = tid & 15;
        float s = b_fc[o];
        for (int k = 0; k < HH; ++k)
            s = fmaf(Hf[r][k], W_fc[o * HH + k], s);
        __builtin_nontemporal_store(s, &out[(b0 + r) * 10 + o]);
    }
}

extern "C" void kernel_launch(void* const* d_in, const int* in_sizes, int n_in,
                              void* d_out, int out_size, void* d_ws, size_t ws_size,
                              hipStream_t stream) {
    const float* x    = (const float*)d_in[0];
    const float* W_ih = (const float*)d_in[1];
    const float* W_hh = (const float*)d_in[2];
    const float* b_ih = (const float*)d_in[3];
    const float* b_hh = (const float*)d_in[4];
    const float* W_fc = (const float*)d_in[5];
    const float* b_fc = (const float*)d_in[6];
    float* out = (float*)d_out;

    rnn_mfma2<<<dim3(8192 / BB), dim3(NT), 0, stream>>>(
        x, W_ih, W_hh, b_ih, b_hh, W_fc, b_fc, out);
}